// Round 11
// baseline (293.918 us; speedup 1.0000x reference)
//
#include <hip/hip_runtime.h>

// s_gcn via bf16-split MFMA, two fused GEMM stages.
// R8: spill-free, bias2 fold, 2 barriers/subtile, reg x-prefetch -> 163us,
//     VALUBusy 40% dominated by manual bf16 hi/lo split (~14 VALU ops/elem).
// R9/R10: packed conversion via inline-asm v_cvt_pk_bf16_f32.
// R11: fix R10's NaN — WRITEX even-column map was colg+8 (must be colg+7,
//     col = t*32 + (colg-25) for colg>=25); odd t=1 columns were never
//     written -> stage-1 read uninitialized LDS -> NaN.

typedef short short8 __attribute__((ext_vector_type(8)));
typedef float floatx4 __attribute__((ext_vector_type(4)));

#define K_NUM 3
#define C_IN  64
#define C_OUT 64
#define T_DIM 2048
#define V_DIM 25
#define N_DIM 16

#define TT    2
#define NSUB  16
#define TWIN  (TT*NSUB)          // 32
#define COLS  (TT*32)            // 64

#define WBUF_ELEMS (12*4*64*8)
#define ABUF_OFF   49152
#define ABUF_ELEMS (3*2*2*64*8)
#define B2_OFF     (ABUF_OFF + ABUF_ELEMS*2)
#define B2_ELEMS   (4*2*64*4)

__device__ __forceinline__ unsigned short bf16_rne(float f) {
    unsigned int u = __builtin_bit_cast(unsigned int, f);
    unsigned int r = (u + 0x7FFFu + ((u >> 16) & 1u)) >> 16;
    return (unsigned short)r;
}
__device__ __forceinline__ int swzf(int row) { return (row & 7) ^ ((row >> 2) & 7); }

// pack bf16(fx) into lo16, bf16(fy) into hi16 — one VALU op
__device__ __forceinline__ unsigned int cvt_pk(float fx, float fy) {
    unsigned int r;
    asm("v_cvt_pk_bf16_f32 %0, %1, %2" : "=v"(r) : "v"(fx), "v"(fy));
    return r;
}

// split two f32 into packed (hi,lo) bf16 u32s: ox={hi(fx) lo16, lo(fx) hi16}
// (k-interleaved pair: bits[15:0] = hi-part bf16, bits[31:16] = lo-part bf16)
__device__ __forceinline__ void split2(float fx, float fy,
                                       unsigned int& ox, unsigned int& oy) {
    unsigned int hhp = cvt_pk(fx, fy);                        // {bf16(fx), bf16(fy)}
    float hix = __builtin_bit_cast(float, hhp << 16);
    float hiy = __builtin_bit_cast(float, hhp & 0xFFFF0000u);
    unsigned int llp = cvt_pk(fx - hix, fy - hiy);            // {bf16(rx), bf16(ry)}
    ox = (hhp & 0xFFFFu) | (llp << 16);
    oy = (hhp >> 16) | (llp & 0xFFFF0000u);
}

__global__ void sgcn_prep(const float* __restrict__ W, const float* __restrict__ A,
                          const float* __restrict__ b,
                          unsigned short* __restrict__ wbuf,
                          unsigned short* __restrict__ abuf,
                          float* __restrict__ b2buf) {
    int idx = blockIdx.x * 256 + threadIdx.x;
    if (idx < WBUF_ELEMS) {
        int j = idx & 7, lane = (idx >> 3) & 63, ks = (idx >> 9) & 3, mt = idx >> 11;
        int o  = mt * 16 + (lane & 15);
        int kk = ks * 32 + (lane >> 4) * 8 + j;
        int ci = kk >> 1;
        wbuf[idx] = bf16_rne(W[o * C_IN + ci]);
    }
    if (idx < ABUF_ELEMS) {
        int j = idx & 7, lane = (idx >> 3) & 63, ks = (idx >> 9) & 1, nt = (idx >> 10) & 1, k = idx >> 11;
        int w  = nt * 16 + (lane & 15);
        int kk = ks * 32 + (lane >> 4) * 8 + j;
        int v  = kk >> 1;
        float val = (v < V_DIM && w < V_DIM) ? A[(k * V_DIM + v) * V_DIM + w] : 0.f;
        abuf[idx] = bf16_rne(val);
    }
    if (idx < B2_ELEMS) {
        int r = idx & 3, lane = (idx >> 2) & 63, nt = (idx >> 8) & 1, mt2 = idx >> 9;
        int c = mt2 * 16 + (lane >> 4) * 4 + r;
        int w = nt * 16 + (lane & 15);
        float val = 0.f;
        if (w < V_DIM) {
            for (int k = 0; k < K_NUM; ++k) {
                float cs = 0.f;
                for (int v = 0; v < V_DIM; ++v) cs += A[(k * V_DIM + v) * V_DIM + w];
                val += b[k * C_OUT + c] * cs;
            }
        }
        b2buf[idx] = val;
    }
}

__global__ __launch_bounds__(512)
void sgcn_main(const float* __restrict__ x,
               const unsigned short* __restrict__ wbuf,
               const unsigned short* __restrict__ abuf,
               const float* __restrict__ b2buf,
               float* __restrict__ out) {
    __shared__ unsigned short Xt[COLS * 128];           // 16 KB
    __shared__ unsigned short H2[K_NUM * TT * 64 * 64]; // 48 KB

    const int tid  = threadIdx.x;
    const int lane = tid & 63;
    const int wid  = tid >> 6;
    const int nb   = blockIdx.x >> 6;
    const int t_base = (blockIdx.x & 63) * TWIN;

    const int wm = wid & 1, wn = wid >> 1;   // stage-1: 2m x 4n
    const int mt2 = wid & 3, th = wid >> 2;  // stage-2: 4m x 2t

    floatx4 b2f[2];
    b2f[0] = reinterpret_cast<const floatx4*>(b2buf)[(mt2 * 2 + 0) * 64 + lane];
    b2f[1] = reinterpret_cast<const floatx4*>(b2buf)[(mt2 * 2 + 1) * 64 + lane];

    // zero never-written padded Xt cols (25..31, 57..63)
    for (int i = tid; i < 14 * 64; i += 512) {
        int pc = i >> 6, ci = i & 63;
        int col = (pc < 7) ? (25 + pc) : (50 + pc);
        ((unsigned int*)Xt)[(col * 64 + ci) ^ (swzf(col) * 4)] = 0u;
    }

    const int bcol = wn * 16 + (lane & 15);
    const int t_c  = bcol >> 5, v_c = bcol & 31;
    const int c_a  = mt2 * 16 + (lane & 15);

    float2 xp[4];
    const float2* xbase = reinterpret_cast<const float2*>(
        x + ((size_t)nb * C_IN * T_DIM + t_base) * V_DIM);

    auto LOADX = [&](int ts) {
        const float2* xsrc = xbase + (size_t)ts * TT * V_DIM / 2;
        #pragma unroll
        for (int p = 0; p < 4; ++p) {
            int u = tid + p * 512;
            if (u < 1600)
                xp[p] = xsrc[(size_t)(u / 25) * (T_DIM * V_DIM / 2) + (u % 25)];
        }
    };
    auto WRITEX = [&]() {
        #pragma unroll
        for (int p = 0; p < 4; ++p) {
            int u = tid + p * 512;
            if (u < 1600) {
                int ci = u / 25, q = u % 25;
                int colg = 2 * q;
                int col0 = (colg     >= 25) ? (colg + 7)     : colg;       // t*32+v
                int col1 = (colg + 1 >= 25) ? (colg + 1 + 7) : (colg + 1);
                unsigned int o0, o1;
                split2(xp[p].x, xp[p].y, o0, o1);
                ((unsigned int*)Xt)[(col0 * 64 + ci) ^ (swzf(col0) * 4)] = o0;
                ((unsigned int*)Xt)[(col1 * 64 + ci) ^ (swzf(col1) * 4)] = o1;
            }
        }
    };

    LOADX(0);

    #pragma unroll 1
    for (int ts = 0; ts < NSUB; ++ts) {
        WRITEX();            // Xt(ts); WAR-safe vs stage-1(ts-1) reads
        __syncthreads();     // barrier A

        // ---- stage-1: H = Wcat * Xcat (M=192 N=64 K=128) ----
        short8 bfr[4];
        #pragma unroll
        for (int ks = 0; ks < 4; ++ks)
            bfr[ks] = ((short8*)Xt)[(bcol * 16 + ks * 4 + (lane >> 4)) ^ swzf(bcol)];

        if (ts + 1 < NSUB) LOADX(ts + 1);

        floatx4 acc1[6];
        #pragma unroll
        for (int im = 0; im < 6; ++im) acc1[im] = floatx4{0.f, 0.f, 0.f, 0.f};

        #pragma unroll
        for (int im = 0; im < 6; ++im) {
            int mt = wm * 6 + im;
            #pragma unroll
            for (int ks = 0; ks < 4; ++ks) {
                short8 afr = ((const short8*)wbuf)[(mt * 4 + ks) * 64 + lane];
                acc1[im] = __builtin_amdgcn_mfma_f32_16x16x32_bf16(afr, bfr[ks], acc1[im], 0, 0, 0);
            }
        }

        // H2 writes: pairs (r0,r1),(r2,r3) through v_cvt_pk_bf16_f32
        #pragma unroll
        for (int im = 0; im < 6; ++im) {
            int mt = wm * 6 + im;
            #pragma unroll
            for (int rp = 0; rp < 2; ++rp) {
                int o0 = mt * 16 + (lane >> 4) * 4 + rp * 2;
                unsigned int w0, w1;
                split2(acc1[im][rp * 2], acc1[im][rp * 2 + 1], w0, w1);
                int k0 = o0 >> 6, c0 = o0 & 63;
                int k1 = (o0 + 1) >> 6, c1 = (o0 + 1) & 63;
                int row0 = (k0 * TT + t_c) * 64 + c0;
                int row1 = (k1 * TT + t_c) * 64 + c1;
                ((unsigned int*)H2)[(row0 * 32 + v_c) ^ (swzf(c0) * 4)] = w0;
                ((unsigned int*)H2)[(row1 * 32 + v_c) ^ (swzf(c1) * 4)] = w1;
            }
        }
        __syncthreads();     // barrier B: H2 ready

        // ---- stage-2: OUT = sum_k H_k * At_k (M=64 N=32 K=64) ----
        floatx4 acc2[2];
        acc2[0] = b2f[0];
        acc2[1] = b2f[1];
        #pragma unroll
        for (int k = 0; k < K_NUM; ++k) {
            short8 ha[2];
            int row = (k * TT + th) * 64 + c_a;
            #pragma unroll
            for (int ks = 0; ks < 2; ++ks)
                ha[ks] = ((short8*)H2)[(row * 8 + ks * 4 + (lane >> 4)) ^ swzf(c_a)];
            #pragma unroll
            for (int nt = 0; nt < 2; ++nt) {
                #pragma unroll
                for (int ks = 0; ks < 2; ++ks) {
                    short8 ab = ((const short8*)abuf)[((k * 2 + nt) * 2 + ks) * 64 + lane];
                    acc2[nt] = __builtin_amdgcn_mfma_f32_16x16x32_bf16(ha[ks], ab, acc2[nt], 0, 0, 0);
                }
            }
        }

        const int tg = t_base + ts * TT + th;
        const int c0 = mt2 * 16 + (lane >> 4) * 4;
        const int wl = lane & 15;
        #pragma unroll
        for (int r = 0; r < 4; ++r)
            out[((size_t)(nb * C_OUT + c0 + r) * T_DIM + tg) * V_DIM + wl] = acc2[0][r];
        if (wl < 9) {
            #pragma unroll
            for (int r = 0; r < 4; ++r)
                out[((size_t)(nb * C_OUT + c0 + r) * T_DIM + tg) * V_DIM + 16 + wl] = acc2[1][r];
        }
    }
}

extern "C" void kernel_launch(void* const* d_in, const int* in_sizes, int n_in,
                              void* d_out, int out_size, void* d_ws, size_t ws_size,
                              hipStream_t stream) {
    const float* x = (const float*)d_in[0];
    const float* A = (const float*)d_in[1];
    const float* W = (const float*)d_in[2];
    const float* b = (const float*)d_in[3];
    float* out = (float*)d_out;

    unsigned short* wbuf = (unsigned short*)d_ws;
    unsigned short* abuf = (unsigned short*)((char*)d_ws + ABUF_OFF);
    float* b2buf = (float*)((char*)d_ws + B2_OFF);

    sgcn_prep<<<(WBUF_ELEMS + 255) / 256, 256, 0, stream>>>(W, A, b, wbuf, abuf, b2buf);

    dim3 grid(N_DIM * (T_DIM / TWIN));   // 1024 blocks
    sgcn_main<<<grid, 512, 0, stream>>>(x, wbuf, abuf, b2buf, out);
}

// Round 12
// 126.964 us; speedup vs baseline: 2.3150x; 2.3150x over previous
//
#include <hip/hip_runtime.h>

// s_gcn, plain-bf16 MFMA, two fused GEMM stages (R12).
//   stage-1: H^T[col][o] = Xt[col][ci] * W[ci][o], M=64 cols (2t x 32v), N=192 o, K=64
//   stage-2: OUT[c][w] = sum_k H_k[c][v] * A_k[v][w], M=64, N=32, K=32
// R12 rationale: W/A were already hi-only bf16 at absmax 0.125 (thr 0.63);
// x/H hi-lo split was unnecessary precision -> drop it. Stage-1 computes H^T
// so each thread's 4 acc values are consecutive v -> packed b64 H2 writes.
// XOR swizzles on Xt (ci2 ^= ((col>>1)&7)<<2) and H2 (v ^= ((c>>2)&3)<<3)
// derived to make staged writes/reads ~2-way (free) -- kills the 6.45M
// bank-conflict counter carried since R6. W/A/b2 fragments hoisted (invariant).

typedef short short8 __attribute__((ext_vector_type(8)));
typedef float floatx4 __attribute__((ext_vector_type(4)));

#define K_NUM 3
#define C_IN  64
#define C_OUT 64
#define T_DIM 2048
#define V_DIM 25
#define N_DIM 16

#define TT    2
#define NSUB  16
#define TWIN  32

#define WBUF_ELEMS (12*2*64*8)              // [nt12][ks2][lane64][j8] u16 = 12288
#define ABUF_OFF   (WBUF_ELEMS*2)           // 24576 B
#define ABUF_ELEMS (3*2*64*8)               // [k3][nt2][lane64][j8] u16 = 3072
#define B2_OFF     (ABUF_OFF + ABUF_ELEMS*2)  // 30720 B
#define B2_ELEMS   (4*2*64*4)               // [mt2_4][nt2][lane64][r4] f32

__device__ __forceinline__ unsigned short bf16_rne(float f) {
    unsigned int u = __builtin_bit_cast(unsigned int, f);
    unsigned int r = (u + 0x7FFFu + ((u >> 16) & 1u)) >> 16;
    return (unsigned short)r;
}

__global__ void sgcn_prep(const float* __restrict__ W, const float* __restrict__ A,
                          const float* __restrict__ b,
                          unsigned short* __restrict__ wbuf,
                          unsigned short* __restrict__ abuf,
                          float* __restrict__ b2buf) {
    int idx = blockIdx.x * 256 + threadIdx.x;
    if (idx < WBUF_ELEMS) {   // B-operand: n=o (lane&15), k=ci ((lane>>4)*8+j)
        int j = idx & 7, lane = (idx >> 3) & 63, ks = (idx >> 9) & 1, nt = idx >> 10;
        int o  = nt * 16 + (lane & 15);
        int ci = ks * 32 + ((lane >> 4) & 3) * 8 + j;
        wbuf[idx] = bf16_rne(W[o * C_IN + ci]);
    }
    if (idx < ABUF_ELEMS) {   // B-operand: n=w, k=v (K=32)
        int j = idx & 7, lane = (idx >> 3) & 63, nt = (idx >> 9) & 1, k = idx >> 10;
        int w = nt * 16 + (lane & 15);
        int v = ((lane >> 4) & 3) * 8 + j;
        abuf[idx] = (v < V_DIM && w < V_DIM) ? bf16_rne(A[(k * V_DIM + v) * V_DIM + w])
                                             : (unsigned short)0;
    }
    if (idx < B2_ELEMS) {     // bias folded through stage-2: sum_k b_kc * sum_v A[k][v][w]
        int r = idx & 3, lane = (idx >> 2) & 63, nt = (idx >> 8) & 1, mt2 = idx >> 9;
        int c = mt2 * 16 + ((lane >> 4) & 3) * 4 + r;
        int w = nt * 16 + (lane & 15);
        float val = 0.f;
        if (w < V_DIM) {
            for (int k = 0; k < K_NUM; ++k) {
                float cs = 0.f;
                for (int v = 0; v < V_DIM; ++v) cs += A[(k * V_DIM + v) * V_DIM + w];
                val += b[k * C_OUT + c] * cs;
            }
        }
        b2buf[idx] = val;
    }
}

__global__ __launch_bounds__(512)
void sgcn_main(const float* __restrict__ x,
               const unsigned short* __restrict__ wbuf,
               const unsigned short* __restrict__ abuf,
               const float* __restrict__ b2buf,
               float* __restrict__ out) {
    __shared__ __align__(16) unsigned short Xt[64 * 64];         // [col][ci^swz]  8 KB
    __shared__ __align__(16) unsigned short H2[K_NUM * TT * 64 * 32]; // [k][t][c][v^swz] 24 KB

    const int tid  = threadIdx.x;
    const int lane = tid & 63;
    const int wid  = tid >> 6;
    const int nb   = blockIdx.x >> 6;
    const int t_base = (blockIdx.x & 63) * TWIN;

    const int wm2 = wid & 1;   // stage-1: col half (= t), 2 m-tiles
    const int wq  = wid >> 1;  // stage-1: o quarter (3 n-tiles)
    const int mt2 = wid & 3, th = wid >> 2;   // stage-2: 4 c-tiles x 2 t

    // ---- hoisted loop-invariant fragments ----
    short8 wfr[3][2];
    #pragma unroll
    for (int ni = 0; ni < 3; ++ni)
        #pragma unroll
        for (int ks = 0; ks < 2; ++ks)
            wfr[ni][ks] = ((const short8*)wbuf)[(((wq * 3 + ni) * 2 + ks) * 64) + lane];
    short8 afr2[3][2];
    #pragma unroll
    for (int k = 0; k < 3; ++k)
        #pragma unroll
        for (int nt = 0; nt < 2; ++nt)
            afr2[k][nt] = ((const short8*)abuf)[((k * 2 + nt) * 64) + lane];
    floatx4 b2f[2];
    b2f[0] = reinterpret_cast<const floatx4*>(b2buf)[(mt2 * 2 + 0) * 64 + lane];
    b2f[1] = reinterpret_cast<const floatx4*>(b2buf)[(mt2 * 2 + 1) * 64 + lane];

    // zero never-written Xt pad cols (25..31, 57..63): whole rows, swizzle-safe
    for (int i = tid; i < 14 * 32; i += 512) {
        int pc = i >> 5, ciw = i & 31;
        int col = (pc < 7) ? (25 + pc) : (50 + pc);
        ((unsigned int*)Xt)[col * 32 + ciw] = 0u;
    }

    // ---- x prefetch: element u -> rows (2*ci2, 2*ci2+1), col cg ----
    float xa[4], xb[4];
    const float* xptr = x + ((size_t)nb * C_IN * T_DIM + t_base) * V_DIM;

    auto LOADX = [&](int ts) {
        const float* s = xptr + ts * TT * V_DIM;
        #pragma unroll
        for (int p = 0; p < 4; ++p) {
            int u = tid + p * 512;
            if (u < 1600) {
                int ci2 = u / 50, cg = u % 50;
                size_t off = (size_t)(2 * ci2) * (T_DIM * V_DIM) + cg;
                xa[p] = s[off];
                xb[p] = s[off + T_DIM * V_DIM];
            }
        }
    };
    auto WRITEX = [&]() {
        #pragma unroll
        for (int p = 0; p < 4; ++p) {
            int u = tid + p * 512;
            if (u < 1600) {
                int ci2 = u / 50, cg = u % 50;
                int t = cg / 25, v = cg - t * 25;
                int col = t * 32 + v;
                unsigned int pk = (unsigned int)bf16_rne(xa[p]) |
                                  ((unsigned int)bf16_rne(xb[p]) << 16);
                int sw = ci2 ^ (((col >> 1) & 7) << 2);
                ((unsigned int*)Xt)[col * 32 + sw] = pk;
            }
        }
    };

    LOADX(0);

    #pragma unroll 1
    for (int ts = 0; ts < NSUB; ++ts) {
        WRITEX();            // Xt(ts); safe: stage-1(ts-1) reads ended before barrier B(ts-1)
        __syncthreads();     // barrier A: Xt ready, stage-2(ts-1) H2 reads done

        // ---- stage-1: H^T = Xt * W  (M=64 col, N=192 o, K=64) ----
        short8 xfr[2][2];
        #pragma unroll
        for (int mi = 0; mi < 2; ++mi) {
            int acol = (wm2 * 2 + mi) * 16 + (lane & 15);
            #pragma unroll
            for (int ks = 0; ks < 2; ++ks) {
                int blk = (ks * 4 + ((lane >> 4) & 3)) ^ ((acol >> 1) & 7);
                xfr[mi][ks] = *(const short8*)&((unsigned int*)Xt)[acol * 32 + blk * 4];
            }
        }

        if (ts + 1 < NSUB) LOADX(ts + 1);   // hide HBM under MFMA

        floatx4 acc1[2][3];
        #pragma unroll
        for (int mi = 0; mi < 2; ++mi)
            #pragma unroll
            for (int ni = 0; ni < 3; ++ni)
                acc1[mi][ni] = floatx4{0.f, 0.f, 0.f, 0.f};

        #pragma unroll
        for (int mi = 0; mi < 2; ++mi)
            #pragma unroll
            for (int ni = 0; ni < 3; ++ni)
                #pragma unroll
                for (int ks = 0; ks < 2; ++ks)
                    acc1[mi][ni] = __builtin_amdgcn_mfma_f32_16x16x32_bf16(
                        xfr[mi][ks], wfr[ni][ks], acc1[mi][ni], 0, 0, 0);

        // ---- H2 write: thread holds 4 consecutive v for fixed (t=wm2, o) -> b64 ----
        #pragma unroll
        for (int mi = 0; mi < 2; ++mi) {
            int vb = mi * 16 + ((lane >> 4) & 3) * 4;
            #pragma unroll
            for (int ni = 0; ni < 3; ++ni) {
                int o = wq * 48 + ni * 16 + (lane & 15);
                int k = o >> 6, c = o & 63;
                int swv = vb ^ (((c >> 2) & 3) << 3);
                unsigned long long lo =
                    (unsigned long long)((unsigned int)bf16_rne(acc1[mi][ni][0]) |
                                         ((unsigned int)bf16_rne(acc1[mi][ni][1]) << 16));
                unsigned long long hi =
                    (unsigned long long)((unsigned int)bf16_rne(acc1[mi][ni][2]) |
                                         ((unsigned int)bf16_rne(acc1[mi][ni][3]) << 16));
                int idx16 = ((k * TT + wm2) * 64 + c) * 32 + swv;   // aligned 4
                ((unsigned long long*)H2)[idx16 >> 2] = lo | (hi << 32);
            }
        }
        __syncthreads();     // barrier B: H2 ready

        // ---- stage-2: OUT[c][w] = sum_k H_k * A_k  (M=64, N=32, K=32) ----
        floatx4 acc2[2];
        acc2[0] = b2f[0];
        acc2[1] = b2f[1];
        const int c_a = mt2 * 16 + (lane & 15);
        #pragma unroll
        for (int k = 0; k < K_NUM; ++k) {
            int row = (k * TT + th) * 64 + c_a;
            int blk = ((lane >> 4) & 3) ^ ((c_a >> 2) & 3);
            short8 ha = *(const short8*)&((unsigned int*)H2)[row * 16 + blk * 4];
            #pragma unroll
            for (int nt = 0; nt < 2; ++nt)
                acc2[nt] = __builtin_amdgcn_mfma_f32_16x16x32_bf16(
                    ha, afr2[k][nt], acc2[nt], 0, 0, 0);
        }

        const int tg = t_base + ts * TT + th;
        const int c0 = mt2 * 16 + ((lane >> 4) & 3) * 4;
        const int wl = lane & 15;
        #pragma unroll
        for (int r = 0; r < 4; ++r)
            out[((size_t)(nb * C_OUT + c0 + r) * T_DIM + tg) * V_DIM + wl] = acc2[0][r];
        if (wl < 9) {
            #pragma unroll
            for (int r = 0; r < 4; ++r)
                out[((size_t)(nb * C_OUT + c0 + r) * T_DIM + tg) * V_DIM + 16 + wl] = acc2[1][r];
        }
    }
}

extern "C" void kernel_launch(void* const* d_in, const int* in_sizes, int n_in,
                              void* d_out, int out_size, void* d_ws, size_t ws_size,
                              hipStream_t stream) {
    const float* x = (const float*)d_in[0];
    const float* A = (const float*)d_in[1];
    const float* W = (const float*)d_in[2];
    const float* b = (const float*)d_in[3];
    float* out = (float*)d_out;

    unsigned short* wbuf = (unsigned short*)d_ws;
    unsigned short* abuf = (unsigned short*)((char*)d_ws + ABUF_OFF);
    float* b2buf = (float*)((char*)d_ws + B2_OFF);

    sgcn_prep<<<(WBUF_ELEMS + 255) / 256, 256, 0, stream>>>(W, A, b, wbuf, abuf, b2buf);

    dim3 grid(N_DIM * (T_DIM / TWIN));   // 1024 blocks x 512 threads
    sgcn_main<<<grid, 512, 0, stream>>>(x, wbuf, abuf, b2buf, out);
}

// Round 13
// 122.937 us; speedup vs baseline: 2.3908x; 1.0328x over previous
//
#include <hip/hip_runtime.h>

// s_gcn, plain-bf16 MFMA, two fused GEMM stages (R12 structure).
// R13: single-barrier pipelined double-buffer.
//   - Xt[2] (16KB) + H2[2] (48KB): per iteration after ONE barrier:
//       stage-1(ts):   read Xt[ts&1]  -> MFMA -> write H2[ts&1]
//       WRITEX(ts+1):  regs -> Xt[(ts+1)&1]
//       stage-2(ts-1): read H2[(ts-1)&1] -> MFMA -> global store
//     All three touch disjoint buffers; every RAW/WAR pair is separated by
//     exactly one barrier (buf parity alternates). 32 -> 17 barriers/block.
//   - WRITEX is now ds_write_b128 per (ci-octet, col): 4x fewer LDS write
//     instrs, start-bank (ciq^f(col))*4 spans all 8 groups -> ~2-way
//     (R12's u32 writes could only reach 8 banks per ci2 -> ~6-way, which
//     is why SQ_LDS_BANK_CONFLICT rose to 7.96M).

typedef short short8 __attribute__((ext_vector_type(8)));
typedef float floatx4 __attribute__((ext_vector_type(4)));
typedef unsigned int uintx4 __attribute__((ext_vector_type(4)));

#define K_NUM 3
#define C_IN  64
#define C_OUT 64
#define T_DIM 2048
#define V_DIM 25
#define N_DIM 16

#define TT    2
#define NSUB  16
#define TWIN  32
#define XROW  51200   // T_DIM*V_DIM

#define WBUF_ELEMS (12*2*64*8)
#define ABUF_OFF   (WBUF_ELEMS*2)
#define ABUF_ELEMS (3*2*64*8)
#define B2_OFF     (ABUF_OFF + ABUF_ELEMS*2)
#define B2_ELEMS   (4*2*64*4)

__device__ __forceinline__ unsigned short bf16_rne(float f) {
    unsigned int u = __builtin_bit_cast(unsigned int, f);
    unsigned int r = (u + 0x7FFFu + ((u >> 16) & 1u)) >> 16;
    return (unsigned short)r;
}

__global__ void sgcn_prep(const float* __restrict__ W, const float* __restrict__ A,
                          const float* __restrict__ b,
                          unsigned short* __restrict__ wbuf,
                          unsigned short* __restrict__ abuf,
                          float* __restrict__ b2buf) {
    int idx = blockIdx.x * 256 + threadIdx.x;
    if (idx < WBUF_ELEMS) {   // B-op: n=o, k=ci
        int j = idx & 7, lane = (idx >> 3) & 63, ks = (idx >> 9) & 1, nt = idx >> 10;
        int o  = nt * 16 + (lane & 15);
        int ci = ks * 32 + ((lane >> 4) & 3) * 8 + j;
        wbuf[idx] = bf16_rne(W[o * C_IN + ci]);
    }
    if (idx < ABUF_ELEMS) {   // B-op: n=w, k=v
        int j = idx & 7, lane = (idx >> 3) & 63, nt = (idx >> 9) & 1, k = idx >> 10;
        int w = nt * 16 + (lane & 15);
        int v = ((lane >> 4) & 3) * 8 + j;
        abuf[idx] = (v < V_DIM && w < V_DIM) ? bf16_rne(A[(k * V_DIM + v) * V_DIM + w])
                                             : (unsigned short)0;
    }
    if (idx < B2_ELEMS) {     // bias folded through stage-2
        int r = idx & 3, lane = (idx >> 2) & 63, nt = (idx >> 8) & 1, mt2 = idx >> 9;
        int c = mt2 * 16 + ((lane >> 4) & 3) * 4 + r;
        int w = nt * 16 + (lane & 15);
        float val = 0.f;
        if (w < V_DIM) {
            for (int k = 0; k < K_NUM; ++k) {
                float cs = 0.f;
                for (int v = 0; v < V_DIM; ++v) cs += A[(k * V_DIM + v) * V_DIM + w];
                val += b[k * C_OUT + c] * cs;
            }
        }
        b2buf[idx] = val;
    }
}

__global__ __launch_bounds__(512)
void sgcn_main(const float* __restrict__ x,
               const unsigned short* __restrict__ wbuf,
               const unsigned short* __restrict__ abuf,
               const float* __restrict__ b2buf,
               float* __restrict__ out) {
    __shared__ __align__(16) unsigned int   Xt[2][64 * 32];              // 2 x 8 KB
    __shared__ __align__(16) unsigned short H2[2][K_NUM * TT * 64 * 32]; // 2 x 24 KB

    const int tid  = threadIdx.x;
    const int lane = tid & 63;
    const int wid  = tid >> 6;
    const int nb   = blockIdx.x >> 6;
    const int t_base = (blockIdx.x & 63) * TWIN;

    const int wm2 = wid & 1;   // stage-1: col half (= t)
    const int wq  = wid >> 1;  // stage-1: o quarter
    const int mt2 = wid & 3, th = wid >> 2;   // stage-2: 4 c-tiles x 2 t

    // ---- hoisted loop-invariant fragments ----
    short8 wfr[3][2];
    #pragma unroll
    for (int ni = 0; ni < 3; ++ni)
        #pragma unroll
        for (int ks = 0; ks < 2; ++ks)
            wfr[ni][ks] = ((const short8*)wbuf)[(((wq * 3 + ni) * 2 + ks) * 64) + lane];
    short8 afr2[3][2];
    #pragma unroll
    for (int k = 0; k < 3; ++k)
        #pragma unroll
        for (int nt = 0; nt < 2; ++nt)
            afr2[k][nt] = ((const short8*)abuf)[((k * 2 + nt) * 64) + lane];
    floatx4 b2f[2];
    b2f[0] = reinterpret_cast<const floatx4*>(b2buf)[(mt2 * 2 + 0) * 64 + lane];
    b2f[1] = reinterpret_cast<const floatx4*>(b2buf)[(mt2 * 2 + 1) * 64 + lane];

    // zero never-written Xt pad cols (25..31, 57..63) in BOTH buffers
    for (int i = tid; i < 2 * 14 * 32; i += 512) {
        int bsel = i >= 14 * 32;
        int j = i - bsel * 14 * 32;
        int pc = j >> 5, ciw = j & 31;
        int col = (pc < 7) ? (25 + pc) : (50 + pc);
        Xt[bsel][col * 32 + ciw] = 0u;
    }

    // ---- x prefetch: one b128 item per thread (400 active) ----
    float xq[8];
    const float* xptr = x + ((size_t)nb * C_IN * T_DIM + t_base) * V_DIM;
    const int ciq = tid / 50, cg = tid % 50;       // item coords (tid<400)
    const int icol = (cg / 25) * 32 + (cg % 25);   // t*32 + v
    const int isw  = (ciq ^ ((icol >> 1) & 7)) * 4;

    auto LOADX = [&](int ts) {
        if (tid < 400) {
            const float* s = xptr + ts * (TT * V_DIM) + (size_t)(ciq * 8) * XROW + cg;
            #pragma unroll
            for (int r = 0; r < 8; ++r) xq[r] = s[(size_t)r * XROW];
        }
    };
    auto WRITEX = [&](int bsel) {
        if (tid < 400) {
            uintx4 pk;
            #pragma unroll
            for (int j = 0; j < 4; ++j)
                pk[j] = (unsigned int)bf16_rne(xq[2 * j]) |
                        ((unsigned int)bf16_rne(xq[2 * j + 1]) << 16);
            *reinterpret_cast<uintx4*>(&Xt[bsel][icol * 32 + isw]) = pk;
        }
    };

    LOADX(0);
    WRITEX(0);
    LOADX(1);

    #pragma unroll 1
    for (int ts = 0; ts <= NSUB; ++ts) {
        __syncthreads();   // the only barrier: fences Xt[cur] & H2[prv] producers
        const int cur = ts & 1, prv = 1 - cur;

        floatx4 acc1[2][3];
        short8 xfr[2][2];
        if (ts < NSUB) {
            // ---- stage-1 reads: H^T = Xt * W  (M=64 col, N=192 o, K=64) ----
            #pragma unroll
            for (int mi = 0; mi < 2; ++mi) {
                int acol = (wm2 * 2 + mi) * 16 + (lane & 15);
                #pragma unroll
                for (int ks = 0; ks < 2; ++ks) {
                    int blk = (ks * 4 + ((lane >> 4) & 3)) ^ ((acol >> 1) & 7);
                    xfr[mi][ks] = *(const short8*)&Xt[cur][acol * 32 + blk * 4];
                }
            }
        }

        // stage-2(ts-1) reads issued early (independent buffer)
        short8 ha[3];
        if (ts >= 1) {
            const int c_a = mt2 * 16 + (lane & 15);
            #pragma unroll
            for (int k = 0; k < K_NUM; ++k) {
                int row = (k * TT + th) * 64 + c_a;
                int blk = ((lane >> 4) & 3) ^ ((c_a >> 2) & 3);
                ha[k] = *(const short8*)&((const unsigned int*)H2[prv])[row * 16 + blk * 4];
            }
        }

        if (ts + 1 < NSUB) WRITEX(cur ^ 1);    // Xt[nxt]; disjoint from all reads
        if (ts + 2 < NSUB) LOADX(ts + 2);      // refill regs; hides under MFMA

        if (ts < NSUB) {
            #pragma unroll
            for (int mi = 0; mi < 2; ++mi)
                #pragma unroll
                for (int ni = 0; ni < 3; ++ni)
                    acc1[mi][ni] = floatx4{0.f, 0.f, 0.f, 0.f};
            #pragma unroll
            for (int mi = 0; mi < 2; ++mi)
                #pragma unroll
                for (int ni = 0; ni < 3; ++ni)
                    #pragma unroll
                    for (int ks = 0; ks < 2; ++ks)
                        acc1[mi][ni] = __builtin_amdgcn_mfma_f32_16x16x32_bf16(
                            xfr[mi][ks], wfr[ni][ks], acc1[mi][ni], 0, 0, 0);

            // H2[cur] write: 4 consecutive v per thread -> b64
            #pragma unroll
            for (int mi = 0; mi < 2; ++mi) {
                int vb = mi * 16 + ((lane >> 4) & 3) * 4;
                #pragma unroll
                for (int ni = 0; ni < 3; ++ni) {
                    int o = wq * 48 + ni * 16 + (lane & 15);
                    int k = o >> 6, c = o & 63;
                    int swv = vb ^ (((c >> 2) & 3) << 3);
                    unsigned long long lo =
                        (unsigned long long)((unsigned int)bf16_rne(acc1[mi][ni][0]) |
                                             ((unsigned int)bf16_rne(acc1[mi][ni][1]) << 16));
                    unsigned long long hi =
                        (unsigned long long)((unsigned int)bf16_rne(acc1[mi][ni][2]) |
                                             ((unsigned int)bf16_rne(acc1[mi][ni][3]) << 16));
                    int idx16 = ((k * TT + wm2) * 64 + c) * 32 + swv;
                    ((unsigned long long*)H2[cur])[idx16 >> 2] = lo | (hi << 32);
                }
            }
        }

        if (ts >= 1) {
            // ---- stage-2(ts-1): OUT[c][w] = sum_k H_k * A_k ----
            floatx4 acc2[2];
            acc2[0] = b2f[0];
            acc2[1] = b2f[1];
            #pragma unroll
            for (int k = 0; k < K_NUM; ++k)
                #pragma unroll
                for (int nt = 0; nt < 2; ++nt)
                    acc2[nt] = __builtin_amdgcn_mfma_f32_16x16x32_bf16(
                        ha[k], afr2[k][nt], acc2[nt], 0, 0, 0);

            const int tg = t_base + (ts - 1) * TT + th;
            const int c0 = mt2 * 16 + ((lane >> 4) & 3) * 4;
            const int wl = lane & 15;
            #pragma unroll
            for (int r = 0; r < 4; ++r)
                out[((size_t)(nb * C_OUT + c0 + r) * T_DIM + tg) * V_DIM + wl] = acc2[0][r];
            if (wl < 9) {
                #pragma unroll
                for (int r = 0; r < 4; ++r)
                    out[((size_t)(nb * C_OUT + c0 + r) * T_DIM + tg) * V_DIM + 16 + wl] = acc2[1][r];
            }
        }
    }
}

extern "C" void kernel_launch(void* const* d_in, const int* in_sizes, int n_in,
                              void* d_out, int out_size, void* d_ws, size_t ws_size,
                              hipStream_t stream) {
    const float* x = (const float*)d_in[0];
    const float* A = (const float*)d_in[1];
    const float* W = (const float*)d_in[2];
    const float* b = (const float*)d_in[3];
    float* out = (float*)d_out;

    unsigned short* wbuf = (unsigned short*)d_ws;
    unsigned short* abuf = (unsigned short*)((char*)d_ws + ABUF_OFF);
    float* b2buf = (float*)((char*)d_ws + B2_OFF);

    sgcn_prep<<<(WBUF_ELEMS + 255) / 256, 256, 0, stream>>>(W, A, b, wbuf, abuf, b2buf);

    dim3 grid(N_DIM * (T_DIM / TWIN));   // 1024 blocks x 512 threads
    sgcn_main<<<grid, 512, 0, stream>>>(x, wbuf, abuf, b2buf, out);
}